// Round 1
// baseline (85.051 us; speedup 1.0000x reference)
//
#include <hip/hip_runtime.h>
#include <math.h>

#define BB 8
#define FF 64
#define NN 256
#define EPSF 1e-9f

// ws layout (floats):
// [0..7]   sum over f of trace[b,f]
// [8..15]  sum over f of trace[b,f]^2
// [16..23] sum over f of trace_sq[b,f]
// [24..31] mean_b[b]
// [32..39] inv_std[b]
// [40..103] g[f] = weight*exp(weight_exp)+weight_bias

__global__ __launch_bounds__(32) void k_init(float* __restrict__ ws) {
    int t = threadIdx.x;
    if (t < 24) ws[t] = 0.f;
}

__global__ __launch_bounds__(256) void k_traces(const float* __restrict__ x,
                                                const float* __restrict__ mask,
                                                float* __restrict__ ws) {
    __shared__ float md[NN];          // mask^2 for this batch
    __shared__ float T1[64][65];
    __shared__ float T2[64][65];
    __shared__ float red[4][2];
    const int t  = threadIdx.x;
    const int bf = blockIdx.x;
    const int b  = bf >> 6;           // F = 64
    const float* __restrict__ xm = x + (size_t)bf * (NN * NN);

    {
        float m = mask[b * NN + t];
        md[t] = m * m;
    }
    __syncthreads();

    const int lane = t & 63;
    const int w    = t >> 6;
    float acc2 = 0.f;   // trace_sq partial
    float trp  = 0.f;   // trace partial

    for (int it = 0; it < 4; ++it) {
        const int i0 = it << 6;
        for (int kt = it; kt < 4; ++kt) {
            const int k0 = kt << 6;
            // cooperative tile loads: float4 global, scalar LDS stores (padded)
            #pragma unroll
            for (int rr = 0; rr < 4; ++rr) {
                int idx4 = t + (rr << 8);        // 0..1023
                int a    = idx4 >> 4;            // 0..63
                int c4   = (idx4 & 15) << 2;     // 0,4,...,60
                float4 v = *(const float4*)(xm + (size_t)(i0 + a) * NN + k0 + c4);
                T1[a][c4 + 0] = v.x; T1[a][c4 + 1] = v.y;
                T1[a][c4 + 2] = v.z; T1[a][c4 + 3] = v.w;
                if (kt > it) {
                    float4 u = *(const float4*)(xm + (size_t)(k0 + a) * NN + i0 + c4);
                    T2[a][c4 + 0] = u.x; T2[a][c4 + 1] = u.y;
                    T2[a][c4 + 2] = u.z; T2[a][c4 + 3] = u.w;
                }
            }
            __syncthreads();
            if (kt > it) {
                #pragma unroll
                for (int s = 0; s < 16; ++s) {
                    int a = w + (s << 2);
                    acc2 += T1[a][lane] * T2[lane][a] * (md[i0 + a] + md[k0 + lane]);
                }
            } else {
                #pragma unroll
                for (int s = 0; s < 16; ++s) {
                    int a = w + (s << 2);
                    acc2 += T1[a][lane] * T1[lane][a] * md[i0 + a];
                    if (lane == a) trp += T1[a][a] * md[i0 + a];
                }
            }
            __syncthreads();
        }
    }

    // 64-lane wave reduction
    #pragma unroll
    for (int off = 32; off > 0; off >>= 1) {
        acc2 += __shfl_down(acc2, off);
        trp  += __shfl_down(trp,  off);
    }
    if (lane == 0) { red[w][0] = trp; red[w][1] = acc2; }
    __syncthreads();
    if (t == 0) {
        float trace = red[0][0] + red[1][0] + red[2][0] + red[3][0];
        float tsq   = red[0][1] + red[1][1] + red[2][1] + red[3][1];
        atomicAdd(&ws[b],      trace);
        atomicAdd(&ws[8 + b],  trace * trace);
        atomicAdd(&ws[16 + b], tsq);
    }
}

__global__ __launch_bounds__(64) void k_finish(const float* __restrict__ mask,
                                               const float* __restrict__ wt,
                                               const float* __restrict__ wexp,
                                               const float* __restrict__ wbias,
                                               float* __restrict__ ws) {
    int t = threadIdx.x;
    ws[40 + t] = wt[t] * expf(wexp[t]) + wbias[t];
    if (t < BB) {
        float n = 0.f;
        for (int i = 0; i < NN; ++i) {
            float m = mask[t * NN + i];
            n += m * m;
        }
        float n2 = fmaxf(n - 1.f, 1.f);
        float st   = ws[t];
        float st2  = ws[8 + t];
        float stsq = ws[16 + t];
        float mean_b = st / ((float)FF * n);
        float var_b  = stsq / ((float)FF * n2) - st2 / ((float)FF * n * n2);
        ws[24 + t] = mean_b;
        ws[32 + t] = 1.f / sqrtf(var_b + EPSF);
    }
}

__global__ __launch_bounds__(256) void k_out(const float* __restrict__ x,
                                             const float* __restrict__ mask,
                                             const float* __restrict__ bias,
                                             const float* __restrict__ ws,
                                             float* __restrict__ out) {
    const int total4 = (BB * FF * NN * NN) >> 2;   // 8,388,608
    const int stride = gridDim.x * blockDim.x;
    for (int idx4 = blockIdx.x * blockDim.x + threadIdx.x; idx4 < total4; idx4 += stride) {
        int e = idx4 << 2;                 // flat element index, < 2^25
        int j = e & (NN - 1);
        int i = (e >> 8) & (NN - 1);
        int f = (e >> 16) & (FF - 1);
        int b = e >> 22;
        float4 xv = ((const float4*)x)[idx4];
        float  mi = mask[(b << 8) + i];                       // wave-uniform
        float4 mj = ((const float4*)mask)[((b << 8) + j) >> 2];
        float meanb   = ws[24 + b];
        float inv_std = ws[32 + b];
        float g  = ws[40 + f];
        float bs = bias[f];
        float s  = mi * inv_std * g;
        float4 o;
        o.x = (xv.x - (i == j     ? meanb : 0.f)) * mj.x * s + (i == j     ? bs : 0.f);
        o.y = (xv.y - (i == j + 1 ? meanb : 0.f)) * mj.y * s + (i == j + 1 ? bs : 0.f);
        o.z = (xv.z - (i == j + 2 ? meanb : 0.f)) * mj.z * s + (i == j + 2 ? bs : 0.f);
        o.w = (xv.w - (i == j + 3 ? meanb : 0.f)) * mj.w * s + (i == j + 3 ? bs : 0.f);
        ((float4*)out)[idx4] = o;
    }
}

extern "C" void kernel_launch(void* const* d_in, const int* in_sizes, int n_in,
                              void* d_out, int out_size, void* d_ws, size_t ws_size,
                              hipStream_t stream) {
    const float* x     = (const float*)d_in[0];
    const float* mask  = (const float*)d_in[1];
    const float* wt    = (const float*)d_in[2];
    const float* wexp  = (const float*)d_in[3];
    const float* wbias = (const float*)d_in[4];
    const float* bias  = (const float*)d_in[5];
    float* out = (float*)d_out;
    float* ws  = (float*)d_ws;

    hipLaunchKernelGGL(k_init,   dim3(1),       dim3(32),  0, stream, ws);
    hipLaunchKernelGGL(k_traces, dim3(BB * FF), dim3(256), 0, stream, x, mask, ws);
    hipLaunchKernelGGL(k_finish, dim3(1),       dim3(64),  0, stream, mask, wt, wexp, wbias, ws);
    hipLaunchKernelGGL(k_out,    dim3(2048),    dim3(256), 0, stream, x, mask, bias, ws, out);
}

// Round 3
// 66.411 us; speedup vs baseline: 1.2807x; 1.2807x over previous
//
#include <hip/hip_runtime.h>
#include <math.h>

#define BB 8
#define FF 64
#define NN 256
#define EPSF 1e-9f

typedef float floatx4 __attribute__((ext_vector_type(4)));

// ws layout (floats):
// [0..1023]    trace partial per (bf, half)    (bh = bf*2+half)
// [1024..2047] trace_sq partial per (bf, half)
// [2048..2055] mean_b[b]
// [2056..2063] inv_std[b]
// [2064..2127] g[f] = weight*exp(weight_exp)+weight_bias

__global__ __launch_bounds__(256) void k_traces(const float* __restrict__ x,
                                                const float* __restrict__ mask,
                                                float* __restrict__ ws) {
    __shared__ float md[NN];          // mask^2 for this batch
    __shared__ float T1[64][65];
    __shared__ float T2[64][65];
    __shared__ float red[4][2];
    const int t    = threadIdx.x;
    const int bh   = blockIdx.x;      // 0..1023
    const int bf   = bh >> 1;
    const int half = bh & 1;
    const int b    = bf >> 6;         // F = 64
    const float* __restrict__ xm = x + (size_t)bf * (NN * NN);

    {
        float m = mask[b * NN + t];
        md[t] = m * m;
    }
    __syncthreads();

    const int lane = t & 63;
    const int w    = t >> 6;
    float acc2 = 0.f;   // trace_sq partial
    float trp  = 0.f;   // trace partial

    // Tile schedule: 2 diagonal tiles + 3 off-diagonal pairs per half (8 tile loads each)
    constexpr int IT0[5] = {0, 1, 0, 0, 0};
    constexpr int KT0[5] = {0, 1, 1, 2, 3};
    constexpr int IT1[5] = {2, 3, 1, 1, 2};
    constexpr int KT1[5] = {2, 3, 2, 3, 3};

    #pragma unroll
    for (int e = 0; e < 5; ++e) {
        const int it = half ? IT1[e] : IT0[e];
        const int kt = half ? KT1[e] : KT0[e];
        const int i0 = it << 6;
        const int k0 = kt << 6;
        const bool diag = (it == kt);
        // cooperative tile loads: float4 global, scalar LDS stores (padded)
        #pragma unroll
        for (int rr = 0; rr < 4; ++rr) {
            int idx4 = t + (rr << 8);        // 0..1023
            int a    = idx4 >> 4;            // 0..63
            int c4   = (idx4 & 15) << 2;     // 0,4,...,60
            float4 v = *(const float4*)(xm + (size_t)(i0 + a) * NN + k0 + c4);
            T1[a][c4 + 0] = v.x; T1[a][c4 + 1] = v.y;
            T1[a][c4 + 2] = v.z; T1[a][c4 + 3] = v.w;
            if (!diag) {
                float4 u = *(const float4*)(xm + (size_t)(k0 + a) * NN + i0 + c4);
                T2[a][c4 + 0] = u.x; T2[a][c4 + 1] = u.y;
                T2[a][c4 + 2] = u.z; T2[a][c4 + 3] = u.w;
            }
        }
        __syncthreads();
        if (!diag) {
            #pragma unroll
            for (int s = 0; s < 16; ++s) {
                int a = w + (s << 2);
                acc2 += T1[a][lane] * T2[lane][a] * (md[i0 + a] + md[k0 + lane]);
            }
        } else {
            #pragma unroll
            for (int s = 0; s < 16; ++s) {
                int a = w + (s << 2);
                acc2 += T1[a][lane] * T1[lane][a] * md[i0 + a];
                if (lane == a) trp += T1[a][a] * md[i0 + a];
            }
        }
        __syncthreads();
    }

    // 64-lane wave reduction
    #pragma unroll
    for (int off = 32; off > 0; off >>= 1) {
        acc2 += __shfl_down(acc2, off);
        trp  += __shfl_down(trp,  off);
    }
    if (lane == 0) { red[w][0] = trp; red[w][1] = acc2; }
    __syncthreads();
    if (t == 0) {
        float trace = red[0][0] + red[1][0] + red[2][0] + red[3][0];
        float tsq   = red[0][1] + red[1][1] + red[2][1] + red[3][1];
        ws[bh]        = trace;
        ws[1024 + bh] = tsq;
    }
}

// One wave per batch b (8 waves), lane = f. No atomics.
__global__ __launch_bounds__(512) void k_finish(const float* __restrict__ mask,
                                                const float* __restrict__ wt,
                                                const float* __restrict__ wexp,
                                                const float* __restrict__ wbias,
                                                float* __restrict__ ws) {
    const int t    = threadIdx.x;
    const int b    = t >> 6;
    const int lane = t & 63;
    float trace = ws[2 * t] + ws[2 * t + 1];
    float tsq   = ws[1024 + 2 * t] + ws[1024 + 2 * t + 1];
    float tr2   = trace * trace;
    float nn = 0.f;
    #pragma unroll
    for (int r = 0; r < 4; ++r) {
        float m = mask[b * NN + lane + (r << 6)];
        nn += m * m;
    }
    #pragma unroll
    for (int off = 32; off > 0; off >>= 1) {
        trace += __shfl_down(trace, off);
        tr2   += __shfl_down(tr2, off);
        tsq   += __shfl_down(tsq, off);
        nn    += __shfl_down(nn, off);
    }
    if (lane == 0) {
        float n  = nn;
        float n2 = fmaxf(n - 1.f, 1.f);
        float mean_b = trace / (64.f * n);
        float var_b  = tsq / (64.f * n2) - tr2 / (64.f * n * n2);
        ws[2048 + b] = mean_b;
        ws[2056 + b] = 1.f / sqrtf(var_b + EPSF);
    }
    if (t < FF) ws[2064 + t] = wt[t] * expf(wexp[t]) + wbias[t];
}

__global__ __launch_bounds__(256) void k_out(const float* __restrict__ x,
                                             const float* __restrict__ mask,
                                             const float* __restrict__ bias,
                                             const float* __restrict__ ws,
                                             float* __restrict__ out) {
    const int total4 = (BB * FF * NN * NN) >> 2;   // 8,388,608
    const int stride = gridDim.x * blockDim.x;
    for (int idx4 = blockIdx.x * blockDim.x + threadIdx.x; idx4 < total4; idx4 += stride) {
        int e = idx4 << 2;                 // flat element index, < 2^25
        int j = e & (NN - 1);
        int i = (e >> 8) & (NN - 1);
        int f = (e >> 16) & (FF - 1);
        int b = e >> 22;
        float4 xv = ((const float4*)x)[idx4];
        float  mi = mask[(b << 8) + i];                       // wave-uniform
        float4 mj = ((const float4*)mask)[((b << 8) + j) >> 2];
        float meanb   = ws[2048 + b];
        float inv_std = ws[2056 + b];
        float g  = ws[2064 + f];
        float bs = bias[f];
        float s  = mi * inv_std * g;
        floatx4 o;
        o.x = (xv.x - (i == j     ? meanb : 0.f)) * mj.x * s + (i == j     ? bs : 0.f);
        o.y = (xv.y - (i == j + 1 ? meanb : 0.f)) * mj.y * s + (i == j + 1 ? bs : 0.f);
        o.z = (xv.z - (i == j + 2 ? meanb : 0.f)) * mj.z * s + (i == j + 2 ? bs : 0.f);
        o.w = (xv.w - (i == j + 3 ? meanb : 0.f)) * mj.w * s + (i == j + 3 ? bs : 0.f);
        __builtin_nontemporal_store(o, &((floatx4*)out)[idx4]);
    }
}

extern "C" void kernel_launch(void* const* d_in, const int* in_sizes, int n_in,
                              void* d_out, int out_size, void* d_ws, size_t ws_size,
                              hipStream_t stream) {
    const float* x     = (const float*)d_in[0];
    const float* mask  = (const float*)d_in[1];
    const float* wt    = (const float*)d_in[2];
    const float* wexp  = (const float*)d_in[3];
    const float* wbias = (const float*)d_in[4];
    const float* bias  = (const float*)d_in[5];
    float* out = (float*)d_out;
    float* ws  = (float*)d_ws;

    hipLaunchKernelGGL(k_traces, dim3(BB * FF * 2), dim3(256), 0, stream, x, mask, ws);
    hipLaunchKernelGGL(k_finish, dim3(1),           dim3(512), 0, stream, mask, wt, wexp, wbias, ws);
    hipLaunchKernelGGL(k_out,    dim3(2048),        dim3(256), 0, stream, x, mask, bias, ws, out);
}

// Round 5
// 65.735 us; speedup vs baseline: 1.2939x; 1.0103x over previous
//
#include <hip/hip_runtime.h>
#include <math.h>

#define BB 8
#define FF 64
#define NN 256
#define EPSF 1e-9f

typedef float floatx4 __attribute__((ext_vector_type(4)));

// ws layout (floats):
// [0..1023]    trace partial per (bf, half)   (bh = bf*2 + half)
// [1024..2047] trace_sq partial per (bf, half)

// Tile schedule per half: jobs 0,1 are diagonal tiles; jobs 2..4 are
// off-diagonal pairs. diag(e) == (e < 2) for BOTH halves.
__device__ __forceinline__ int jit(int half, int e) {
    constexpr int IT0[5] = {0, 1, 0, 0, 0};
    constexpr int IT1[5] = {2, 3, 1, 1, 2};
    return half ? IT1[e] : IT0[e];
}
__device__ __forceinline__ int jkt(int half, int e) {
    constexpr int KT0[5] = {0, 1, 1, 2, 3};
    constexpr int KT1[5] = {2, 3, 2, 3, 3};
    return half ? KT1[e] : KT0[e];
}

__global__ __launch_bounds__(256) void k_traces(const float* __restrict__ x,
                                                const float* __restrict__ mask,
                                                float* __restrict__ ws) {
    __shared__ float md[NN];
    __shared__ float T1[64][65];
    __shared__ float T2[64][65];
    __shared__ float red[4][2];
    const int t    = threadIdx.x;
    const int bh   = blockIdx.x;      // 0..1023
    const int bf   = bh >> 1;
    const int half = bh & 1;
    const int b    = bf >> 6;
    const float* __restrict__ xm = x + (size_t)bf * (NN * NN);

    { float m = mask[b * NN + t]; md[t] = m * m; }

    const int lane = t & 63;
    const int w    = t >> 6;
    const int la   = t >> 4;          // 0..15: row sub-index for staging
    const int lc4  = (t & 15) << 2;   // 0,4,...,60: col for staging
    float acc2 = 0.f, trp = 0.f;

    float4 p1[4], p2[4];

    // ---- prefetch job 0 (diagonal) ----
    {
        const int i0 = jit(half, 0) << 6, k0 = jkt(half, 0) << 6;
        #pragma unroll
        for (int rr = 0; rr < 4; ++rr) {
            int a = la + (rr << 4);
            p1[rr] = *(const float4*)(xm + (size_t)(i0 + a) * NN + k0 + lc4);
        }
    }

    #pragma unroll
    for (int e = 0; e < 5; ++e) {
        const bool diag = (e < 2);
        const int i0 = jit(half, e) << 6;
        const int k0 = jkt(half, e) << 6;

        // stage regs -> LDS
        #pragma unroll
        for (int rr = 0; rr < 4; ++rr) {
            int a = la + (rr << 4);
            T1[a][lc4 + 0] = p1[rr].x; T1[a][lc4 + 1] = p1[rr].y;
            T1[a][lc4 + 2] = p1[rr].z; T1[a][lc4 + 3] = p1[rr].w;
            if (!diag) {
                T2[a][lc4 + 0] = p2[rr].x; T2[a][lc4 + 1] = p2[rr].y;
                T2[a][lc4 + 2] = p2[rr].z; T2[a][lc4 + 3] = p2[rr].w;
            }
        }
        __syncthreads();

        // issue next job's loads while computing current
        if (e < 4) {
            const int ni0 = jit(half, e + 1) << 6;
            const int nk0 = jkt(half, e + 1) << 6;
            #pragma unroll
            for (int rr = 0; rr < 4; ++rr) {
                int a = la + (rr << 4);
                p1[rr] = *(const float4*)(xm + (size_t)(ni0 + a) * NN + nk0 + lc4);
                if (e + 1 >= 2)
                    p2[rr] = *(const float4*)(xm + (size_t)(nk0 + a) * NN + ni0 + lc4);
            }
        }

        if (!diag) {
            #pragma unroll
            for (int s = 0; s < 16; ++s) {
                int a = w + (s << 2);
                acc2 += T1[a][lane] * T2[lane][a] * (md[i0 + a] + md[k0 + lane]);
            }
        } else {
            #pragma unroll
            for (int s = 0; s < 16; ++s) {
                int a = w + (s << 2);
                acc2 += T1[a][lane] * T1[lane][a] * md[i0 + a];
                if (lane == a) trp += T1[a][a] * md[i0 + a];
            }
        }
        __syncthreads();
    }

    #pragma unroll
    for (int off = 32; off > 0; off >>= 1) {
        acc2 += __shfl_down(acc2, off);
        trp  += __shfl_down(trp,  off);
    }
    if (lane == 0) { red[w][0] = trp; red[w][1] = acc2; }
    __syncthreads();
    if (t == 0) {
        ws[bh]        = red[0][0] + red[1][0] + red[2][0] + red[3][0];
        ws[1024 + bh] = red[0][1] + red[1][1] + red[2][1] + red[3][1];
    }
}

__global__ __launch_bounds__(256) void k_out(const float* __restrict__ x,
                                             const float* __restrict__ mask,
                                             const float* __restrict__ wt,
                                             const float* __restrict__ wexp,
                                             const float* __restrict__ wbias,
                                             const float* __restrict__ bias,
                                             const float* __restrict__ ws,
                                             float* __restrict__ out) {
    __shared__ float smean[BB], sistd[BB], sg[FF], sb[FF];
    const int t    = threadIdx.x;
    const int lane = t & 63;
    const int w    = t >> 6;

    // stats prologue: wave w reduces batches w and w+4; lane = feature
    for (int bb = w; bb < BB; bb += 4) {
        const int base = (bb << 7) + (lane << 1);
        float trf = ws[base] + ws[base + 1];
        float tsf = ws[1024 + base] + ws[1024 + base + 1];
        float tr2 = trf * trf;
        float m0 = mask[(bb << 8) + lane];
        float m1 = mask[(bb << 8) + lane + 64];
        float m2 = mask[(bb << 8) + lane + 128];
        float m3 = mask[(bb << 8) + lane + 192];
        float nn = m0 * m0 + m1 * m1 + m2 * m2 + m3 * m3;
        #pragma unroll
        for (int off = 32; off > 0; off >>= 1) {
            trf += __shfl_down(trf, off);
            tr2 += __shfl_down(tr2, off);
            tsf += __shfl_down(tsf, off);
            nn  += __shfl_down(nn,  off);
        }
        if (lane == 0) {
            float n  = nn;
            float n2 = fmaxf(n - 1.f, 1.f);
            smean[bb] = trf / (64.f * n);
            sistd[bb] = 1.f / sqrtf(tsf / (64.f * n2) - tr2 / (64.f * n * n2) + EPSF);
        }
    }
    if (t < FF) { sg[t] = wt[t] * expf(wexp[t]) + wbias[t]; sb[t] = bias[t]; }
    __syncthreads();

    const int total4 = (BB * FF * NN * NN) >> 2;   // 8,388,608
    const int stride = gridDim.x * blockDim.x;
    for (int idx4 = blockIdx.x * blockDim.x + t; idx4 < total4; idx4 += stride) {
        int e = idx4 << 2;
        int j = e & (NN - 1);
        int i = (e >> 8) & (NN - 1);
        int f = (e >> 16) & (FF - 1);
        int b = e >> 22;
        float4 xv = ((const float4*)x)[idx4];
        float  mi = mask[(b << 8) + i];
        float4 mj = ((const float4*)mask)[((b << 8) + j) >> 2];
        float meanb   = smean[b];
        float inv_std = sistd[b];
        float g  = sg[f];
        float bs = sb[f];
        float s  = mi * inv_std * g;
        floatx4 o;
        o.x = (xv.x - (i == j     ? meanb : 0.f)) * mj.x * s + (i == j     ? bs : 0.f);
        o.y = (xv.y - (i == j + 1 ? meanb : 0.f)) * mj.y * s + (i == j + 1 ? bs : 0.f);
        o.z = (xv.z - (i == j + 2 ? meanb : 0.f)) * mj.z * s + (i == j + 2 ? bs : 0.f);
        o.w = (xv.w - (i == j + 3 ? meanb : 0.f)) * mj.w * s + (i == j + 3 ? bs : 0.f);
        __builtin_nontemporal_store(o, &((floatx4*)out)[idx4]);
    }
}

extern "C" void kernel_launch(void* const* d_in, const int* in_sizes, int n_in,
                              void* d_out, int out_size, void* d_ws, size_t ws_size,
                              hipStream_t stream) {
    const float* x     = (const float*)d_in[0];
    const float* mask  = (const float*)d_in[1];
    const float* wt    = (const float*)d_in[2];
    const float* wexp  = (const float*)d_in[3];
    const float* wbias = (const float*)d_in[4];
    const float* bias  = (const float*)d_in[5];
    float* out = (float*)d_out;
    float* ws  = (float*)d_ws;

    hipLaunchKernelGGL(k_traces, dim3(BB * FF * 2), dim3(256), 0, stream, x, mask, ws);
    hipLaunchKernelGGL(k_out,    dim3(2048),        dim3(256), 0, stream,
                       x, mask, wt, wexp, wbias, bias, ws, out);
}